// Round 16
// baseline (371.859 us; speedup 1.0000x reference)
//
#include <hip/hip_runtime.h>

// x [16384,512] f32, codebook [8192,512] f32 -> out[n] = codebook[argmin_k ||x_n-c_k||^2]
// bf16 MFMA GEMM, 256(cb)x128(x) blocks, BK=32. KEY CHANGE (r16): x-operand bypasses
// LDS -- loaded global->register (L1-served, 1-tile prefetch). Only codebook staged in
// LDS (pair-line, 0-conflict, r12-verified). LDS traffic/blk-tile: 88KB -> 48KB, below
// the MFMA floor. Operand-swapped so argmin axis is lane-local; per-lane top-3 + LDS
// key merge; guaranteed-inclusive fp64 refine fused with gather.

#define MROWS 16384
#define KCB   8192
#define DDIM  512
#define NKT   16             // K-tiles of BK=32
#define NTILES 64            // stat tiles of 128 cb rows
#define MARGIN 8.0f

typedef unsigned short u16;
typedef unsigned int uint;
typedef __attribute__((ext_vector_type(8))) short bf16x8;
typedef __attribute__((ext_vector_type(4))) float f32x4;

__device__ inline u16 f2bf(float f) {
  unsigned int u = __float_as_uint(f);
  u += 0x7FFFu + ((u >> 16) & 1u);
  return (u16)(u >> 16);
}

__device__ inline void gload16(const void* g, void* l) {
  __builtin_amdgcn_global_load_lds((const __attribute__((address_space(1))) void*)g,
                                   (__attribute__((address_space(3))) void*)l,
                                   16, 0, 0);
}

__device__ inline double shfl_xor_dbl(double v, int m) {
  long long l = __double_as_longlong(v);
  int lo = (int)(l & 0xffffffffLL), hi = (int)(l >> 32);
  lo = __shfl_xor(lo, m, 64);
  hi = __shfl_xor(hi, m, 64);
  return __longlong_as_double(((long long)hi << 32) | (unsigned long long)(unsigned int)lo);
}

__device__ inline float keyval(uint k) {
  uint u = k & 0xFFFFFF80u;
  uint bits = (u & 0x80000000u) ? (u & 0x7FFFFFFFu) : ~u;
  return __uint_as_float(bits);
}

// ---------------- fused conversion kernel ----------------
// blocks [0,4096): x rows; blocks [4096,6144): cb rows (4/block)

__global__ __launch_bounds__(256) void k_conv(const float* __restrict__ x,
                                              const float* __restrict__ cb,
                                              u16* __restrict__ xb,
                                              u16* __restrict__ cbb,
                                              float* __restrict__ cnorm) {
  int b = blockIdx.x;
  if (b < 4096) {
    size_t i = ((size_t)b * 256 + threadIdx.x) * 8;
    float4 a = *(const float4*)(x + i);
    float4 c = *(const float4*)(x + i + 4);
    union { u16 s[8]; uint4 v; } u;
    u.s[0]=f2bf(a.x); u.s[1]=f2bf(a.y); u.s[2]=f2bf(a.z); u.s[3]=f2bf(a.w);
    u.s[4]=f2bf(c.x); u.s[5]=f2bf(c.y); u.s[6]=f2bf(c.z); u.s[7]=f2bf(c.w);
    *(uint4*)(xb + i) = u.v;
  } else {
    int k = (b - 4096) * 4 + (threadIdx.x >> 6);
    int lane = threadIdx.x & 63;
    size_t base = (size_t)k * DDIM + lane * 8;
    float4 a = *(const float4*)(cb + base);
    float4 c = *(const float4*)(cb + base + 4);
    union { u16 s[8]; uint4 v; } u;
    u.s[0]=f2bf(a.x); u.s[1]=f2bf(a.y); u.s[2]=f2bf(a.z); u.s[3]=f2bf(a.w);
    u.s[4]=f2bf(c.x); u.s[5]=f2bf(c.y); u.s[6]=f2bf(c.z); u.s[7]=f2bf(c.w);
    *(uint4*)(cbb + base) = u.v;
    float s = a.x*a.x + a.y*a.y + a.z*a.z + a.w*a.w
            + c.x*c.x + c.y*c.y + c.z*c.z + c.w*c.w;
    #pragma unroll
    for (int m = 1; m < 64; m <<= 1) s += __shfl_xor(s, m, 64);
    if (lane == 0) cnorm[k] = s;
  }
}

// ---------------- 256(cb)x128(x) GEMM, BK=32: A in pair-line LDS, X direct ----------------
// LDS (u16 elems): buf b at b*8192: A (cb 256x32), 128 lines of 128B. Line R holds
// rows {2R,2R+1}; slot s = (row&1)*4 + chunk stored at s' = s ^ (R&7).

__global__ __launch_bounds__(512, 4) void k_gemm_min(
    const u16* __restrict__ Xbf, const u16* __restrict__ Cbf,
    const float* __restrict__ cnorm, uint2* __restrict__ stats)
{
  extern __shared__ __align__(16) u16 lds[];

  int bid = blockIdx.x;          // 4096 blocks
  int xcd = bid & 7;
  int j   = bid >> 3;            // 0..511
  int mTile = xcd * 16 + (j & 15);  // x tiles 0..127
  int nTile = j >> 4;               // cb tiles 0..31
  int rowBase = mTile * 128;     // x rows
  int colBase = nTile * 256;     // cb rows

  int tid = threadIdx.x;
  int lane = tid & 63;
  int wv = tid >> 6;     // 0..7
  int wr = wv & 3;       // cb quarter (M)
  int wc = wv >> 2;      // x half (N)
  int grp = lane >> 4;
  int l15 = lane & 15;

  // A staging source: dest byte tid*16 = line R0=tid>>3, slot' tid&7; inverse map
  const int R0 = tid >> 3;
  const int s0 = (tid & 7) ^ (R0 & 7);
  const int row_st = 2 * R0 + (s0 >> 2);
  const int ch_st  = (s0 & 3) << 3;
  const u16* pA = Cbf + (size_t)(colBase + row_st) * DDIM + ch_st;

  // A reader LDS element offsets (kt-invariant); r12-verified 0-conflict swizzle
  const int lswz = (((((l15 & 1) << 2) | grp) ^ ((l15 >> 1) & 7)) << 3);
  int offA[4];
  #pragma unroll
  for (int i = 0; i < 4; ++i) {
    int rA = wr * 64 + i * 16 + l15;
    offA[i] = (rA >> 1) * 64 + lswz;
  }

  // X direct-from-global pointers (kt offset = kt*32 elems)
  const u16* pX[4];
  #pragma unroll
  for (int ni = 0; ni < 4; ++ni)
    pX[ni] = Xbf + (size_t)(rowBase + wc * 64 + ni * 16 + l15) * DDIM + grp * 8;

  f32x4 acc[4][4];
  #pragma unroll
  for (int mi = 0; mi < 4; ++mi)
    #pragma unroll
    for (int ni = 0; ni < 4; ++ni)
      acc[mi][ni] = (f32x4){0.f, 0.f, 0.f, 0.f};

  bf16x8 xR[2][4];   // double-buffered x fragments (indexed by kt&1, static unroll)

#define STAGE(b_, T)                                                          \
  {                                                                           \
    u16* Ad = lds + (b_) * 8192;                                              \
    gload16(pA + (T) * 32,         (void*)(Ad + tid * 8));                    \
    gload16(pA + 65536 + (T) * 32, (void*)(Ad + 4096 + tid * 8));             \
  }

  STAGE(0, 0);
  STAGE(1, 1);
  #pragma unroll
  for (int ni = 0; ni < 4; ++ni) xR[0][ni] = *(const bf16x8*)(pX[ni]);
  __syncthreads();               // prologue drain

  #pragma unroll
  for (int kt = 0; kt < NKT; ++kt) {
    const int cu = kt & 1;
    // prefetch next K-tile's x fragments (global, L1/L2-served; used NEXT iter)
    if (kt + 1 < NKT) {
      #pragma unroll
      for (int ni = 0; ni < 4; ++ni)
        xR[cu ^ 1][ni] = *(const bf16x8*)(pX[ni] + (kt + 1) * 32);
    }
    const u16* base = lds + cu * 8192;
    bf16x8 cF[4];
    #pragma unroll
    for (int mi = 0; mi < 4; ++mi) cF[mi] = *(const bf16x8*)&base[offA[mi]];
    __builtin_amdgcn_s_setprio(1);
    #pragma unroll
    for (int mi = 0; mi < 4; ++mi)
      #pragma unroll
      for (int ni = 0; ni < 4; ++ni)
        acc[mi][ni] = __builtin_amdgcn_mfma_f32_16x16x32_bf16(cF[mi], xR[cu][ni], acc[mi][ni], 0, 0, 0);
    __builtin_amdgcn_s_setprio(0);
    __syncthreads();             // frees buf cu; drains A-stage issued LAST iteration
    if (kt + 2 < NKT) STAGE(cu, kt + 2);
  }
#undef STAGE

  // ---- epilogue: per-lane top-3 over wave's 64 cb rows (r12-verified) ----
  // D[m=cb][n=x]: x-row = lane&15, cb = (lane>>4)*4 + reg
#define INS(st1, st2, st3, kx)                                     \
  { uint kk_ = (kx);                                               \
    bool lt1 = kk_ < st1, lt2 = kk_ < st2, lt3 = kk_ < st3;        \
    st3 = lt3 ? (lt2 ? st2 : kk_) : st3;                           \
    st2 = lt2 ? (lt1 ? st1 : kk_) : st2;                           \
    st1 = lt1 ? kk_ : st1; }

  uint t1[4], t2[4], t3[4];
  #pragma unroll
  for (int ni = 0; ni < 4; ++ni) { t1[ni] = 0xFFFFFFFFu; t2[ni] = 0xFFFFFFFFu; t3[ni] = 0xFFFFFFFFu; }

  const uint tagBase = (uint)((wr & 1) * 64);   // position within 128-row stat tile
  #pragma unroll
  for (int mi = 0; mi < 4; ++mi) {
    float cnv[4];
    *(float4*)cnv = *(const float4*)&cnorm[colBase + wr * 64 + mi * 16 + grp * 4];
    #pragma unroll
    for (int ni = 0; ni < 4; ++ni) {
      #pragma unroll
      for (int rg = 0; rg < 4; ++rg) {
        float v = cnv[rg] - 2.0f * acc[mi][ni][rg];
        uint u = __float_as_uint(v);
        u = ((int)u < 0) ? ~u : (u | 0x80000000u);
        uint key = (u & 0xFFFFFF80u) | (tagBase + (uint)(mi * 16 + grp * 4 + rg));
        INS(t1[ni], t2[ni], t3[ni], key);
      }
    }
  }
  #pragma unroll
  for (int ni = 0; ni < 4; ++ni) {
    #pragma unroll
    for (int mk = 16; mk <= 32; mk <<= 1) {
      uint o1 = (uint)__shfl_xor((int)t1[ni], mk, 64);
      uint o2 = (uint)__shfl_xor((int)t2[ni], mk, 64);
      uint o3 = (uint)__shfl_xor((int)t3[ni], mk, 64);
      INS(t1[ni], t2[ni], t3[ni], o1);
      INS(t1[ni], t2[ni], t3[ni], o2);
      INS(t1[ni], t2[ni], t3[ni], o3);
    }
  }

  // LDS key-merge across the cb-quarter wave pairs (wr 0+1 -> tile 0, 2+3 -> tile 1)
  uint* scK = (uint*)lds;        // [4 wr][128 xloc][3] = 6 KB (all GEMM reads done)
  if (grp == 0) {
    #pragma unroll
    for (int ni = 0; ni < 4; ++ni) {
      int xloc = wc * 64 + ni * 16 + l15;
      uint* p = &scK[(wr * 128 + xloc) * 3];
      p[0] = t1[ni]; p[1] = t2[ni]; p[2] = t3[ni];
    }
  }
  __syncthreads();
  if (tid < 256) {
    int xr = tid & 127;
    int s  = tid >> 7;           // stat tile within block
    const uint* pa = &scK[((2 * s) * 128 + xr) * 3];
    const uint* pb = &scK[((2 * s + 1) * 128 + xr) * 3];
    uint a1 = pa[0], a2 = pa[1], a3 = pa[2];
    #pragma unroll
    for (int z = 0; z < 3; ++z) INS(a1, a2, a3, pb[z]);
    float v1 = keyval(a1), v2 = keyval(a2), v3 = keyval(a3);
    uint i1 = a1 & 127u, i2 = a2 & 127u;
    uint d2 = min(255u, (uint)((v2 - v1) * 4.0f));   // floor -> conservative-low
    uint d3 = min(255u, (uint)((v3 - v1) * 4.0f));
    uint2 st;
    st.x = __float_as_uint(v1);
    st.y = i1 | (i2 << 7) | (d2 << 14) | (d3 << 22);
    stats[(size_t)(rowBase + xr) * NTILES + nTile * 2 + s] = st;
  }
#undef INS
}

// ---------------- fp64 refinement core ----------------

__device__ inline void eval64(const float4& xa, const float4& xb,
                              const float* __restrict__ cb, int col,
                              double& best, int& bi, int lane) {
  const float* cr = cb + (size_t)col * DDIM + lane * 8;
  float4 ca = *(const float4*)cr;
  float4 cv = *(const float4*)(cr + 4);
  double s = 0.0, d;
  d = (double)xa.x - (double)ca.x; s += d*d;
  d = (double)xa.y - (double)ca.y; s += d*d;
  d = (double)xa.z - (double)ca.z; s += d*d;
  d = (double)xa.w - (double)ca.w; s += d*d;
  d = (double)xb.x - (double)cv.x; s += d*d;
  d = (double)xb.y - (double)cv.y; s += d*d;
  d = (double)xb.z - (double)cv.z; s += d*d;
  d = (double)xb.w - (double)cv.w; s += d*d;
  #pragma unroll
  for (int m = 1; m < 64; m <<= 1) s += shfl_xor_dbl(s, m);
  if (s < best || (s == best && col < bi)) { best = s; bi = col; }
}

__device__ inline int refine_row(int n, int lane,
                                 const float* __restrict__ x, const float* __restrict__ cb,
                                 const float* __restrict__ cnorm,
                                 const uint2* __restrict__ stats) {
  uint2 st = stats[(size_t)n * NTILES + lane];   // lane t owns stat tile t
  float m1 = __uint_as_float(st.x);
  int   i1 = st.y & 127, i2 = (st.y >> 7) & 127;
  float m2 = m1 + ((st.y >> 14) & 255u) * 0.25f;
  float m3 = m1 + ((st.y >> 22) & 255u) * 0.25f;
  float g = m1;
  #pragma unroll
  for (int m = 1; m < 64; m <<= 1) g = fminf(g, __shfl_xor(g, m, 64));
  float T = g + MARGIN;
  unsigned long long q1 = __ballot(m1 <= T);
  unsigned long long q2 = __ballot(m2 <= T);
  unsigned long long qr = __ballot(m3 <= T);

  const float* xr = x + (size_t)n * DDIM;
  float4 xa = *(const float4*)(xr + lane * 8);
  float4 xb = *(const float4*)(xr + lane * 8 + 4);

  double best = 1e300;
  int bi = 0x7fffffff;

  while (q1) {
    int t = __ffsll(q1) - 1; q1 &= q1 - 1;
    int col = t * 128 + __shfl(i1, t, 64);
    eval64(xa, xb, cb, col, best, bi, lane);
  }
  while (q2) {
    int t = __ffsll(q2) - 1; q2 &= q2 - 1;
    int col = t * 128 + __shfl(i2, t, 64);
    eval64(xa, xb, cb, col, best, bi, lane);
  }
  while (qr) {
    int t = __ffsll(qr) - 1; qr &= qr - 1;
    for (int c2 = 0; c2 < 128; ++c2) {
      int col2 = t * 128 + c2;
      const float* cr = cb + (size_t)col2 * DDIM + lane * 8;
      float4 ca = *(const float4*)cr;
      float4 cv = *(const float4*)(cr + 4);
      float p = xa.x*ca.x + xa.y*ca.y + xa.z*ca.z + xa.w*ca.w
              + xb.x*cv.x + xb.y*cv.y + xb.z*cv.z + xb.w*cv.w;
      #pragma unroll
      for (int m = 1; m < 64; m <<= 1) p += __shfl_xor(p, m, 64);
      float s32 = cnorm[col2] - 2.0f * p;
      if (s32 <= T) {
        double s = 0.0, dd;
        dd = (double)xa.x - (double)ca.x; s += dd*dd;
        dd = (double)xa.y - (double)ca.y; s += dd*dd;
        dd = (double)xa.z - (double)ca.z; s += dd*dd;
        dd = (double)xa.w - (double)ca.w; s += dd*dd;
        dd = (double)xb.x - (double)cv.x; s += dd*dd;
        dd = (double)xb.y - (double)cv.y; s += dd*dd;
        dd = (double)xb.z - (double)cv.z; s += dd*dd;
        dd = (double)xb.w - (double)cv.w; s += dd*dd;
        #pragma unroll
        for (int m = 1; m < 64; m <<= 1) s += shfl_xor_dbl(s, m);
        if (s < best || (s == best && col2 < bi)) { best = s; bi = col2; }
      }
    }
  }
  return bi;
}

__global__ __launch_bounds__(256) void k_refine(
    const float* __restrict__ x, const float* __restrict__ cb,
    const float* __restrict__ cnorm, const uint2* __restrict__ stats,
    unsigned int* __restrict__ bestOut)
{
  int n = blockIdx.x * 4 + (threadIdx.x >> 6);
  int lane = threadIdx.x & 63;
  int bi = refine_row(n, lane, x, cb, cnorm, stats);
  if (lane == 0) bestOut[n] = (unsigned int)bi;
}

__global__ __launch_bounds__(256) void k_refine_gather(
    const float* __restrict__ x, const float* __restrict__ cb,
    const float* __restrict__ cnorm, const uint2* __restrict__ stats,
    float* __restrict__ out)
{
  int n = blockIdx.x * 4 + (threadIdx.x >> 6);
  int lane = threadIdx.x & 63;
  int bi = refine_row(n, lane, x, cb, cnorm, stats);
  const float4* s = (const float4*)(cb + (size_t)bi * DDIM);
  float4* dp = (float4*)(out + (size_t)n * DDIM);
  dp[lane * 2]     = s[lane * 2];
  dp[lane * 2 + 1] = s[lane * 2 + 1];
}

__global__ __launch_bounds__(256) void k_gather(const float* __restrict__ cb,
                                                const unsigned int* __restrict__ bestIdx,
                                                float* __restrict__ out) {
  int n = blockIdx.x * 4 + (threadIdx.x >> 6);
  int lane = threadIdx.x & 63;
  unsigned int b = bestIdx[n];
  const float4* s = (const float4*)(cb + (size_t)b * DDIM);
  float4* dp = (float4*)(out + (size_t)n * DDIM);
  dp[lane * 2]     = s[lane * 2];
  dp[lane * 2 + 1] = s[lane * 2 + 1];
}

// ---------------- launch ----------------

extern "C" void kernel_launch(void* const* d_in, const int* in_sizes, int n_in,
                              void* d_out, int out_size, void* d_ws, size_t ws_size,
                              hipStream_t stream) {
  const float* x  = (const float*)d_in[0];   // [16384, 512]
  const float* cb = (const float*)d_in[1];   // [8192, 512]
  float* out = (float*)d_out;

  char* ob = (char*)d_out;
  u16* Xbf = (u16*)ob;                          // [0,16M)
  u16* Cbf = (u16*)(ob + 16ull * 1024 * 1024);  // [16M,24M)

  char* wsb = (char*)d_ws;
  float* cnorm = (float*)wsb;                               // 32 KB
  unsigned int* bestIdx = (unsigned int*)(wsb + 32 * 1024); // 64 KB

  const size_t statsBytes = (size_t)MROWS * NTILES * sizeof(uint2);  // 8 MB
  bool fuse = ws_size >= 96 * 1024 + statsBytes;
  uint2* stats = fuse ? (uint2*)(wsb + 96 * 1024)
                      : (uint2*)(ob + 24ull * 1024 * 1024);

  (void)hipFuncSetAttribute((const void*)k_gemm_min,
                            hipFuncAttributeMaxDynamicSharedMemorySize, 16384 * 2);

  k_conv    <<<6144, 256, 0, stream>>>(x, cb, Xbf, Cbf, cnorm);
  k_gemm_min<<<4096, 512, 32768, stream>>>(Xbf, Cbf, cnorm, stats);
  if (fuse) {
    k_refine_gather<<<4096, 256, 0, stream>>>(x, cb, cnorm, stats, out);
  } else {
    k_refine<<<4096, 256, 0, stream>>>(x, cb, cnorm, stats, bestIdx);
    k_gather<<<4096, 256, 0, stream>>>(cb, bestIdx, out);
  }
}

// Round 17
// 245.977 us; speedup vs baseline: 1.5118x; 1.5118x over previous
//
#include <hip/hip_runtime.h>

// x [16384,512] f32, codebook [8192,512] f32 -> out[n] = codebook[argmin_k ||x_n-c_k||^2]
// bf16 MFMA GEMM (round-12 proven config: 256cb x 128x, BK=32, 2-deep pipeline,
// pair-line LDS 0-conflict, 2 blocks/CU). Operand-swapped so argmin axis is lane-local;
// per-lane top-3 + LDS key merge. Round-17: refine fast-path (single-candidate skip)
// + paired candidate evals (overlapped loads); fused gather.

#define MROWS 16384
#define KCB   8192
#define DDIM  512
#define NKT   16             // K-tiles of BK=32
#define NTILES 64            // stat tiles of 128 cb rows
#define MARGIN 8.0f

typedef unsigned short u16;
typedef unsigned int uint;
typedef __attribute__((ext_vector_type(8))) short bf16x8;
typedef __attribute__((ext_vector_type(4))) float f32x4;

__device__ inline u16 f2bf(float f) {
  unsigned int u = __float_as_uint(f);
  u += 0x7FFFu + ((u >> 16) & 1u);
  return (u16)(u >> 16);
}

__device__ inline void gload16(const void* g, void* l) {
  __builtin_amdgcn_global_load_lds((const __attribute__((address_space(1))) void*)g,
                                   (__attribute__((address_space(3))) void*)l,
                                   16, 0, 0);
}

__device__ inline double shfl_xor_dbl(double v, int m) {
  long long l = __double_as_longlong(v);
  int lo = (int)(l & 0xffffffffLL), hi = (int)(l >> 32);
  lo = __shfl_xor(lo, m, 64);
  hi = __shfl_xor(hi, m, 64);
  return __longlong_as_double(((long long)hi << 32) | (unsigned long long)(unsigned int)lo);
}

__device__ inline float keyval(uint k) {
  uint u = k & 0xFFFFFF80u;
  uint bits = (u & 0x80000000u) ? (u & 0x7FFFFFFFu) : ~u;
  return __uint_as_float(bits);
}

// ---------------- conversion kernels (round-12 verified) ----------------

__global__ __launch_bounds__(256) void k_conv_x(const float* __restrict__ x,
                                                u16* __restrict__ xb) {
  size_t i = ((size_t)blockIdx.x * 256 + threadIdx.x) * 8;
  float4 a = *(const float4*)(x + i);
  float4 b = *(const float4*)(x + i + 4);
  union { u16 s[8]; uint4 v; } u;
  u.s[0]=f2bf(a.x); u.s[1]=f2bf(a.y); u.s[2]=f2bf(a.z); u.s[3]=f2bf(a.w);
  u.s[4]=f2bf(b.x); u.s[5]=f2bf(b.y); u.s[6]=f2bf(b.z); u.s[7]=f2bf(b.w);
  *(uint4*)(xb + i) = u.v;
}

__global__ __launch_bounds__(256) void k_conv_cb(const float* __restrict__ cb,
                                                 u16* __restrict__ cbb,
                                                 float* __restrict__ cnorm) {
  int k = blockIdx.x * 4 + (threadIdx.x >> 6);
  int lane = threadIdx.x & 63;
  size_t base = (size_t)k * DDIM + lane * 8;
  float4 a = *(const float4*)(cb + base);
  float4 b = *(const float4*)(cb + base + 4);
  union { u16 s[8]; uint4 v; } u;
  u.s[0]=f2bf(a.x); u.s[1]=f2bf(a.y); u.s[2]=f2bf(a.z); u.s[3]=f2bf(a.w);
  u.s[4]=f2bf(b.x); u.s[5]=f2bf(b.y); u.s[6]=f2bf(b.z); u.s[7]=f2bf(b.w);
  *(uint4*)(cbb + base) = u.v;
  float s = a.x*a.x + a.y*a.y + a.z*a.z + a.w*a.w
          + b.x*b.x + b.y*b.y + b.z*b.z + b.w*b.w;
  #pragma unroll
  for (int m = 1; m < 64; m <<= 1) s += __shfl_xor(s, m, 64);
  if (lane == 0) cnorm[k] = s;
}

// ---------------- 256(cb)x128(x) GEMM, BK=32, pair-line LDS (round-12) ----------------
// LDS (u16 elems): buf b at b*12288: A (cb 256x32) at +0 (128 lines of 128B),
// B (x 128x32) at +8192 (64 lines). Line R holds rows {2R,2R+1}; slot s =
// (row&1)*4 + chunk stored at s' = s ^ (R&7).

__global__ __launch_bounds__(512, 4) void k_gemm_min(
    const u16* __restrict__ Xbf, const u16* __restrict__ Cbf,
    const float* __restrict__ cnorm, uint2* __restrict__ stats)
{
  extern __shared__ __align__(16) u16 lds[];

  int bid = blockIdx.x;          // 4096 blocks
  int xcd = bid & 7;
  int j   = bid >> 3;            // 0..511
  int mTile = xcd * 16 + (j & 15);  // x tiles 0..127
  int nTile = j >> 4;               // cb tiles 0..31
  int rowBase = mTile * 128;     // x rows
  int colBase = nTile * 256;     // cb rows

  int tid = threadIdx.x;
  int lane = tid & 63;
  int wv = tid >> 6;     // 0..7
  int wr = wv & 3;       // cb quarter (M)
  int wc = wv >> 2;      // x half (N)
  int grp = lane >> 4;
  int l15 = lane & 15;

  // staging sources: dest byte tid*16 = line R0=tid>>3, slot' tid&7;
  // inverse map -> source (row, chunk)
  const int R0 = tid >> 3;
  const int s0 = (tid & 7) ^ (R0 & 7);
  const int row_st = 2 * R0 + (s0 >> 2);
  const int ch_st  = (s0 & 3) << 3;            // element offset in row
  const u16* pA = Cbf + (size_t)(colBase + row_st) * DDIM + ch_st;
  const u16* pB = Xbf + (size_t)(rowBase + row_st) * DDIM + ch_st;

  // reader LDS element offsets (kt-invariant); lane swizzle shared by A and X
  const int lswz = (((((l15 & 1) << 2) | grp) ^ ((l15 >> 1) & 7)) << 3);
  int offA[4], offX[4];
  #pragma unroll
  for (int i = 0; i < 4; ++i) {
    int rA = wr * 64 + i * 16 + l15;
    offA[i] = (rA >> 1) * 64 + lswz;
    int rX = wc * 64 + i * 16 + l15;
    offX[i] = 8192 + (rX >> 1) * 64 + lswz;
  }

  f32x4 acc[4][4];
  #pragma unroll
  for (int mi = 0; mi < 4; ++mi)
    #pragma unroll
    for (int ni = 0; ni < 4; ++ni)
      acc[mi][ni] = (f32x4){0.f, 0.f, 0.f, 0.f};

#define STAGE(b_, T)                                                          \
  {                                                                           \
    u16* Ad = lds + (b_) * 12288;                                             \
    gload16(pA + (T) * 32,               (void*)(Ad + tid * 8));              \
    gload16(pA + 65536 + (T) * 32,       (void*)(Ad + 4096 + tid * 8));       \
    gload16(pB + (T) * 32,               (void*)(Ad + 8192 + tid * 8));       \
  }

  STAGE(0, 0);
  STAGE(1, 1);
  __syncthreads();               // prologue drain

  int cur = 0;
  for (int kt = 0; kt < NKT; ++kt) {
    const u16* base = lds + cur * 12288;
    bf16x8 cF[4], xF[4];
    #pragma unroll
    for (int mi = 0; mi < 4; ++mi) cF[mi] = *(const bf16x8*)&base[offA[mi]];
    #pragma unroll
    for (int ni = 0; ni < 4; ++ni) xF[ni] = *(const bf16x8*)&base[offX[ni]];
    __builtin_amdgcn_s_setprio(1);
    #pragma unroll
    for (int mi = 0; mi < 4; ++mi)
      #pragma unroll
      for (int ni = 0; ni < 4; ++ni)
        acc[mi][ni] = __builtin_amdgcn_mfma_f32_16x16x32_bf16(cF[mi], xF[ni], acc[mi][ni], 0, 0, 0);
    __builtin_amdgcn_s_setprio(0);
    __syncthreads();             // frees buf cur; drains stage issued LAST iteration
    if (kt + 2 < NKT) STAGE(cur, kt + 2);
    cur ^= 1;
  }
#undef STAGE

  // ---- epilogue: per-lane top-3 over wave's 64 cb rows ----
  // D[m=cb][n=x]: x-row = lane&15, cb = (lane>>4)*4 + reg
#define INS(st1, st2, st3, kx)                                     \
  { uint kk_ = (kx);                                               \
    bool lt1 = kk_ < st1, lt2 = kk_ < st2, lt3 = kk_ < st3;        \
    st3 = lt3 ? (lt2 ? st2 : kk_) : st3;                           \
    st2 = lt2 ? (lt1 ? st1 : kk_) : st2;                           \
    st1 = lt1 ? kk_ : st1; }

  uint t1[4], t2[4], t3[4];
  #pragma unroll
  for (int ni = 0; ni < 4; ++ni) { t1[ni] = 0xFFFFFFFFu; t2[ni] = 0xFFFFFFFFu; t3[ni] = 0xFFFFFFFFu; }

  const uint tagBase = (uint)((wr & 1) * 64);   // position within 128-row stat tile
  #pragma unroll
  for (int mi = 0; mi < 4; ++mi) {
    float cnv[4];
    *(float4*)cnv = *(const float4*)&cnorm[colBase + wr * 64 + mi * 16 + grp * 4];
    #pragma unroll
    for (int ni = 0; ni < 4; ++ni) {
      #pragma unroll
      for (int rg = 0; rg < 4; ++rg) {
        float v = cnv[rg] - 2.0f * acc[mi][ni][rg];
        uint u = __float_as_uint(v);
        u = ((int)u < 0) ? ~u : (u | 0x80000000u);
        uint key = (u & 0xFFFFFF80u) | (tagBase + (uint)(mi * 16 + grp * 4 + rg));
        INS(t1[ni], t2[ni], t3[ni], key);
      }
    }
  }
  #pragma unroll
  for (int ni = 0; ni < 4; ++ni) {
    #pragma unroll
    for (int mk = 16; mk <= 32; mk <<= 1) {
      uint o1 = (uint)__shfl_xor((int)t1[ni], mk, 64);
      uint o2 = (uint)__shfl_xor((int)t2[ni], mk, 64);
      uint o3 = (uint)__shfl_xor((int)t3[ni], mk, 64);
      INS(t1[ni], t2[ni], t3[ni], o1);
      INS(t1[ni], t2[ni], t3[ni], o2);
      INS(t1[ni], t2[ni], t3[ni], o3);
    }
  }

  // LDS key-merge across the cb-quarter wave pairs (wr 0+1 -> tile 0, 2+3 -> tile 1)
  uint* scK = (uint*)lds;        // [4 wr][128 xloc][3] = 6 KB (all GEMM reads done)
  if (grp == 0) {
    #pragma unroll
    for (int ni = 0; ni < 4; ++ni) {
      int xloc = wc * 64 + ni * 16 + l15;
      uint* p = &scK[(wr * 128 + xloc) * 3];
      p[0] = t1[ni]; p[1] = t2[ni]; p[2] = t3[ni];
    }
  }
  __syncthreads();
  if (tid < 256) {
    int xr = tid & 127;
    int s  = tid >> 7;           // stat tile within block
    const uint* pa = &scK[((2 * s) * 128 + xr) * 3];
    const uint* pb = &scK[((2 * s + 1) * 128 + xr) * 3];
    uint a1 = pa[0], a2 = pa[1], a3 = pa[2];
    #pragma unroll
    for (int z = 0; z < 3; ++z) INS(a1, a2, a3, pb[z]);
    float v1 = keyval(a1), v2 = keyval(a2), v3 = keyval(a3);
    uint i1 = a1 & 127u, i2 = a2 & 127u;
    uint d2 = min(255u, (uint)((v2 - v1) * 4.0f));   // floor -> conservative-low
    uint d3 = min(255u, (uint)((v3 - v1) * 4.0f));
    uint2 st;
    st.x = __float_as_uint(v1);
    st.y = i1 | (i2 << 7) | (d2 << 14) | (d3 << 22);
    stats[(size_t)(rowBase + xr) * NTILES + nTile * 2 + s] = st;
  }
#undef INS
}

// ---------------- fp64 refinement core ----------------

__device__ inline double dist64(const float4& xa, const float4& xb,
                                const float4& ca, const float4& cv, int lane) {
  double s = 0.0, d;
  d = (double)xa.x - (double)ca.x; s += d*d;
  d = (double)xa.y - (double)ca.y; s += d*d;
  d = (double)xa.z - (double)ca.z; s += d*d;
  d = (double)xa.w - (double)ca.w; s += d*d;
  d = (double)xb.x - (double)cv.x; s += d*d;
  d = (double)xb.y - (double)cv.y; s += d*d;
  d = (double)xb.z - (double)cv.z; s += d*d;
  d = (double)xb.w - (double)cv.w; s += d*d;
  #pragma unroll
  for (int m = 1; m < 64; m <<= 1) s += shfl_xor_dbl(s, m);
  return s;
}

__device__ inline void upd(double s, int col, double& best, int& bi) {
  if (s < best || (s == best && col < bi)) { best = s; bi = col; }
}

// paired eval: both rows' loads issue before either reduction (latency overlap)
__device__ inline void eval64_pair(const float4& xa, const float4& xb,
                                   const float* __restrict__ cb, int colA, int colB,
                                   bool hasB, double& best, int& bi, int lane) {
  const float* crA = cb + (size_t)colA * DDIM + lane * 8;
  float4 a0 = *(const float4*)crA;
  float4 a1 = *(const float4*)(crA + 4);
  float4 b0, b1;
  if (hasB) {
    const float* crB = cb + (size_t)colB * DDIM + lane * 8;
    b0 = *(const float4*)crB;
    b1 = *(const float4*)(crB + 4);
  }
  double sA = dist64(xa, xb, a0, a1, lane);
  upd(sA, colA, best, bi);
  if (hasB) {
    double sB = dist64(xa, xb, b0, b1, lane);
    upd(sB, colB, best, bi);
  }
}

__device__ inline int refine_row(int n, int lane,
                                 const float* __restrict__ x, const float* __restrict__ cb,
                                 const float* __restrict__ cnorm,
                                 const uint2* __restrict__ stats) {
  uint2 st = stats[(size_t)n * NTILES + lane];   // lane t owns stat tile t
  float m1 = __uint_as_float(st.x);
  int   i1 = st.y & 127, i2 = (st.y >> 7) & 127;
  float m2 = m1 + ((st.y >> 14) & 255u) * 0.25f;
  float m3 = m1 + ((st.y >> 22) & 255u) * 0.25f;
  float g = m1;
  #pragma unroll
  for (int m = 1; m < 64; m <<= 1) g = fminf(g, __shfl_xor(g, m, 64));
  float T = g + MARGIN;
  unsigned long long q1 = __ballot(m1 <= T);
  unsigned long long q2 = __ballot(m2 <= T);
  unsigned long long qr = __ballot(m3 <= T);

  // fast path: exactly one candidate in q1 and none elsewhere -> it IS the argmin
  // (candidate set provably contains the true argmin; here it's a singleton)
  if (q2 == 0 && qr == 0 && (q1 & (q1 - 1)) == 0) {
    int t = __ffsll(q1) - 1;
    return t * 128 + __shfl(i1, t, 64);
  }

  const float* xr = x + (size_t)n * DDIM;
  float4 xa = *(const float4*)(xr + lane * 8);
  float4 xb = *(const float4*)(xr + lane * 8 + 4);

  double best = 1e300;
  int bi = 0x7fffffff;

  while (q1) {
    int t0 = __ffsll(q1) - 1; q1 &= q1 - 1;
    int colA = t0 * 128 + __shfl(i1, t0, 64);
    int colB = 0; bool hasB = false;
    if (q1) {
      int tB = __ffsll(q1) - 1; q1 &= q1 - 1;
      colB = tB * 128 + __shfl(i1, tB, 64);
      hasB = true;
    }
    eval64_pair(xa, xb, cb, colA, colB, hasB, best, bi, lane);
  }
  while (q2) {
    int t0 = __ffsll(q2) - 1; q2 &= q2 - 1;
    int colA = t0 * 128 + __shfl(i2, t0, 64);
    int colB = 0; bool hasB = false;
    if (q2) {
      int tB = __ffsll(q2) - 1; q2 &= q2 - 1;
      colB = tB * 128 + __shfl(i2, tB, 64);
      hasB = true;
    }
    eval64_pair(xa, xb, cb, colA, colB, hasB, best, bi, lane);
  }
  while (qr) {
    int t = __ffsll(qr) - 1; qr &= qr - 1;
    for (int c2 = 0; c2 < 128; ++c2) {
      int col2 = t * 128 + c2;
      const float* cr = cb + (size_t)col2 * DDIM + lane * 8;
      float4 ca = *(const float4*)cr;
      float4 cv = *(const float4*)(cr + 4);
      float p = xa.x*ca.x + xa.y*ca.y + xa.z*ca.z + xa.w*ca.w
              + xb.x*cv.x + xb.y*cv.y + xb.z*cv.z + xb.w*cv.w;
      #pragma unroll
      for (int m = 1; m < 64; m <<= 1) p += __shfl_xor(p, m, 64);
      float s32 = cnorm[col2] - 2.0f * p;
      if (s32 <= T) {
        double s = dist64(xa, xb, ca, cv, lane);
        upd(s, col2, best, bi);
      }
    }
  }
  return bi;
}

__global__ __launch_bounds__(256) void k_refine(
    const float* __restrict__ x, const float* __restrict__ cb,
    const float* __restrict__ cnorm, const uint2* __restrict__ stats,
    unsigned int* __restrict__ bestOut)
{
  int n = blockIdx.x * 4 + (threadIdx.x >> 6);
  int lane = threadIdx.x & 63;
  int bi = refine_row(n, lane, x, cb, cnorm, stats);
  if (lane == 0) bestOut[n] = (unsigned int)bi;
}

__global__ __launch_bounds__(256) void k_refine_gather(
    const float* __restrict__ x, const float* __restrict__ cb,
    const float* __restrict__ cnorm, const uint2* __restrict__ stats,
    float* __restrict__ out)
{
  int n = blockIdx.x * 4 + (threadIdx.x >> 6);
  int lane = threadIdx.x & 63;
  int bi = refine_row(n, lane, x, cb, cnorm, stats);
  const float4* s = (const float4*)(cb + (size_t)bi * DDIM);
  float4* dp = (float4*)(out + (size_t)n * DDIM);
  dp[lane * 2]     = s[lane * 2];
  dp[lane * 2 + 1] = s[lane * 2 + 1];
}

__global__ __launch_bounds__(256) void k_gather(const float* __restrict__ cb,
                                                const unsigned int* __restrict__ bestIdx,
                                                float* __restrict__ out) {
  int n = blockIdx.x * 4 + (threadIdx.x >> 6);
  int lane = threadIdx.x & 63;
  unsigned int b = bestIdx[n];
  const float4* s = (const float4*)(cb + (size_t)b * DDIM);
  float4* dp = (float4*)(out + (size_t)n * DDIM);
  dp[lane * 2]     = s[lane * 2];
  dp[lane * 2 + 1] = s[lane * 2 + 1];
}

// ---------------- launch ----------------

extern "C" void kernel_launch(void* const* d_in, const int* in_sizes, int n_in,
                              void* d_out, int out_size, void* d_ws, size_t ws_size,
                              hipStream_t stream) {
  const float* x  = (const float*)d_in[0];   // [16384, 512]
  const float* cb = (const float*)d_in[1];   // [8192, 512]
  float* out = (float*)d_out;

  char* ob = (char*)d_out;
  u16* Xbf = (u16*)ob;                          // [0,16M)
  u16* Cbf = (u16*)(ob + 16ull * 1024 * 1024);  // [16M,24M)

  char* wsb = (char*)d_ws;
  float* cnorm = (float*)wsb;                               // 32 KB
  unsigned int* bestIdx = (unsigned int*)(wsb + 32 * 1024); // 64 KB

  const size_t statsBytes = (size_t)MROWS * NTILES * sizeof(uint2);  // 8 MB
  bool fuse = ws_size >= 96 * 1024 + statsBytes;
  uint2* stats = fuse ? (uint2*)(wsb + 96 * 1024)
                      : (uint2*)(ob + 24ull * 1024 * 1024);

  (void)hipFuncSetAttribute((const void*)k_gemm_min,
                            hipFuncAttributeMaxDynamicSharedMemorySize, 49152);

  k_conv_x  <<<4096, 256, 0, stream>>>(x, Xbf);
  k_conv_cb <<<2048, 256, 0, stream>>>(cb, Cbf, cnorm);
  k_gemm_min<<<4096, 512, 49152, stream>>>(Xbf, Cbf, cnorm, stats);
  if (fuse) {
    k_refine_gather<<<4096, 256, 0, stream>>>(x, cb, cnorm, stats, out);
  } else {
    k_refine<<<4096, 256, 0, stream>>>(x, cb, cnorm, stats, bestIdx);
    k_gather<<<4096, 256, 0, stream>>>(cb, bestIdx, out);
  }
}

// Round 18
// 243.608 us; speedup vs baseline: 1.5265x; 1.0097x over previous
//
#include <hip/hip_runtime.h>

// x [16384,512] f32, codebook [8192,512] f32 -> out[n] = codebook[argmin_k ||x_n-c_k||^2]
// bf16 MFMA GEMM (round-12 proven config: 256cb x 128x, BK=32, 2-deep pipeline,
// pair-line LDS 0-conflict). Operand-swapped so argmin axis is lane-local; per-lane
// top-3 + LDS key merge. Round-18: fused conv (1 dispatch), MARGIN 7.0 (bound 6.75),
// refine fast-path + paired evals, fused refine+gather.

#define MROWS 16384
#define KCB   8192
#define DDIM  512
#define NKT   16             // K-tiles of BK=32
#define NTILES 64            // stat tiles of 128 cb rows
#define MARGIN 7.0f          // > worst-case bf16 score-pair error (~6.75)

typedef unsigned short u16;
typedef unsigned int uint;
typedef __attribute__((ext_vector_type(8))) short bf16x8;
typedef __attribute__((ext_vector_type(4))) float f32x4;

__device__ inline u16 f2bf(float f) {
  unsigned int u = __float_as_uint(f);
  u += 0x7FFFu + ((u >> 16) & 1u);
  return (u16)(u >> 16);
}

__device__ inline void gload16(const void* g, void* l) {
  __builtin_amdgcn_global_load_lds((const __attribute__((address_space(1))) void*)g,
                                   (__attribute__((address_space(3))) void*)l,
                                   16, 0, 0);
}

__device__ inline double shfl_xor_dbl(double v, int m) {
  long long l = __double_as_longlong(v);
  int lo = (int)(l & 0xffffffffLL), hi = (int)(l >> 32);
  lo = __shfl_xor(lo, m, 64);
  hi = __shfl_xor(hi, m, 64);
  return __longlong_as_double(((long long)hi << 32) | (unsigned long long)(unsigned int)lo);
}

__device__ inline float keyval(uint k) {
  uint u = k & 0xFFFFFF80u;
  uint bits = (u & 0x80000000u) ? (u & 0x7FFFFFFFu) : ~u;
  return __uint_as_float(bits);
}

// ---------------- fused conversion kernel ----------------
// blocks [0,4096): x rows; blocks [4096,6144): cb rows (4/block)

__global__ __launch_bounds__(256) void k_conv(const float* __restrict__ x,
                                              const float* __restrict__ cb,
                                              u16* __restrict__ xb,
                                              u16* __restrict__ cbb,
                                              float* __restrict__ cnorm) {
  int b = blockIdx.x;
  if (b < 4096) {
    size_t i = ((size_t)b * 256 + threadIdx.x) * 8;
    float4 a = *(const float4*)(x + i);
    float4 c = *(const float4*)(x + i + 4);
    union { u16 s[8]; uint4 v; } u;
    u.s[0]=f2bf(a.x); u.s[1]=f2bf(a.y); u.s[2]=f2bf(a.z); u.s[3]=f2bf(a.w);
    u.s[4]=f2bf(c.x); u.s[5]=f2bf(c.y); u.s[6]=f2bf(c.z); u.s[7]=f2bf(c.w);
    *(uint4*)(xb + i) = u.v;
  } else {
    int k = (b - 4096) * 4 + (threadIdx.x >> 6);
    int lane = threadIdx.x & 63;
    size_t base = (size_t)k * DDIM + lane * 8;
    float4 a = *(const float4*)(cb + base);
    float4 c = *(const float4*)(cb + base + 4);
    union { u16 s[8]; uint4 v; } u;
    u.s[0]=f2bf(a.x); u.s[1]=f2bf(a.y); u.s[2]=f2bf(a.z); u.s[3]=f2bf(a.w);
    u.s[4]=f2bf(c.x); u.s[5]=f2bf(c.y); u.s[6]=f2bf(c.z); u.s[7]=f2bf(c.w);
    *(uint4*)(cbb + base) = u.v;
    float s = a.x*a.x + a.y*a.y + a.z*a.z + a.w*a.w
            + c.x*c.x + c.y*c.y + c.z*c.z + c.w*c.w;
    #pragma unroll
    for (int m = 1; m < 64; m <<= 1) s += __shfl_xor(s, m, 64);
    if (lane == 0) cnorm[k] = s;
  }
}

// ---------------- 256(cb)x128(x) GEMM, BK=32, pair-line LDS (round-12) ----------------
// LDS (u16 elems): buf b at b*12288: A (cb 256x32) at +0 (128 lines of 128B),
// B (x 128x32) at +8192 (64 lines). Line R holds rows {2R, 2R+1}; slot s =
// (row&1)*4 + chunk stored at s' = s ^ (R&7).

__global__ __launch_bounds__(512, 4) void k_gemm_min(
    const u16* __restrict__ Xbf, const u16* __restrict__ Cbf,
    const float* __restrict__ cnorm, uint2* __restrict__ stats)
{
  extern __shared__ __align__(16) u16 lds[];

  int bid = blockIdx.x;          // 4096 blocks
  int xcd = bid & 7;
  int j   = bid >> 3;            // 0..511
  int mTile = xcd * 16 + (j & 15);  // x tiles 0..127
  int nTile = j >> 4;               // cb tiles 0..31
  int rowBase = mTile * 128;     // x rows
  int colBase = nTile * 256;     // cb rows

  int tid = threadIdx.x;
  int lane = tid & 63;
  int wv = tid >> 6;     // 0..7
  int wr = wv & 3;       // cb quarter (M)
  int wc = wv >> 2;      // x half (N)
  int grp = lane >> 4;
  int l15 = lane & 15;

  const int R0 = tid >> 3;
  const int s0 = (tid & 7) ^ (R0 & 7);
  const int row_st = 2 * R0 + (s0 >> 2);
  const int ch_st  = (s0 & 3) << 3;
  const u16* pA = Cbf + (size_t)(colBase + row_st) * DDIM + ch_st;
  const u16* pB = Xbf + (size_t)(rowBase + row_st) * DDIM + ch_st;

  const int lswz = (((((l15 & 1) << 2) | grp) ^ ((l15 >> 1) & 7)) << 3);
  int offA[4], offX[4];
  #pragma unroll
  for (int i = 0; i < 4; ++i) {
    int rA = wr * 64 + i * 16 + l15;
    offA[i] = (rA >> 1) * 64 + lswz;
    int rX = wc * 64 + i * 16 + l15;
    offX[i] = 8192 + (rX >> 1) * 64 + lswz;
  }

  f32x4 acc[4][4];
  #pragma unroll
  for (int mi = 0; mi < 4; ++mi)
    #pragma unroll
    for (int ni = 0; ni < 4; ++ni)
      acc[mi][ni] = (f32x4){0.f, 0.f, 0.f, 0.f};

#define STAGE(b_, T)                                                          \
  {                                                                           \
    u16* Ad = lds + (b_) * 12288;                                             \
    gload16(pA + (T) * 32,               (void*)(Ad + tid * 8));              \
    gload16(pA + 65536 + (T) * 32,       (void*)(Ad + 4096 + tid * 8));       \
    gload16(pB + (T) * 32,               (void*)(Ad + 8192 + tid * 8));       \
  }

  STAGE(0, 0);
  STAGE(1, 1);
  __syncthreads();               // prologue drain

  int cur = 0;
  for (int kt = 0; kt < NKT; ++kt) {
    const u16* base = lds + cur * 12288;
    bf16x8 cF[4], xF[4];
    #pragma unroll
    for (int mi = 0; mi < 4; ++mi) cF[mi] = *(const bf16x8*)&base[offA[mi]];
    #pragma unroll
    for (int ni = 0; ni < 4; ++ni) xF[ni] = *(const bf16x8*)&base[offX[ni]];
    __builtin_amdgcn_s_setprio(1);
    #pragma unroll
    for (int mi = 0; mi < 4; ++mi)
      #pragma unroll
      for (int ni = 0; ni < 4; ++ni)
        acc[mi][ni] = __builtin_amdgcn_mfma_f32_16x16x32_bf16(cF[mi], xF[ni], acc[mi][ni], 0, 0, 0);
    __builtin_amdgcn_s_setprio(0);
    __syncthreads();             // frees buf cur; drains stage issued LAST iteration
    if (kt + 2 < NKT) STAGE(cur, kt + 2);
    cur ^= 1;
  }
#undef STAGE

  // ---- epilogue: per-lane top-3 over wave's 64 cb rows ----
  // D[m=cb][n=x]: x-row = lane&15, cb = (lane>>4)*4 + reg
#define INS(st1, st2, st3, kx)                                     \
  { uint kk_ = (kx);                                               \
    bool lt1 = kk_ < st1, lt2 = kk_ < st2, lt3 = kk_ < st3;        \
    st3 = lt3 ? (lt2 ? st2 : kk_) : st3;                           \
    st2 = lt2 ? (lt1 ? st1 : kk_) : st2;                           \
    st1 = lt1 ? kk_ : st1; }

  uint t1[4], t2[4], t3[4];
  #pragma unroll
  for (int ni = 0; ni < 4; ++ni) { t1[ni] = 0xFFFFFFFFu; t2[ni] = 0xFFFFFFFFu; t3[ni] = 0xFFFFFFFFu; }

  const uint tagBase = (uint)((wr & 1) * 64);
  #pragma unroll
  for (int mi = 0; mi < 4; ++mi) {
    float cnv[4];
    *(float4*)cnv = *(const float4*)&cnorm[colBase + wr * 64 + mi * 16 + grp * 4];
    #pragma unroll
    for (int ni = 0; ni < 4; ++ni) {
      #pragma unroll
      for (int rg = 0; rg < 4; ++rg) {
        float v = cnv[rg] - 2.0f * acc[mi][ni][rg];
        uint u = __float_as_uint(v);
        u = ((int)u < 0) ? ~u : (u | 0x80000000u);
        uint key = (u & 0xFFFFFF80u) | (tagBase + (uint)(mi * 16 + grp * 4 + rg));
        INS(t1[ni], t2[ni], t3[ni], key);
      }
    }
  }
  #pragma unroll
  for (int ni = 0; ni < 4; ++ni) {
    #pragma unroll
    for (int mk = 16; mk <= 32; mk <<= 1) {
      uint o1 = (uint)__shfl_xor((int)t1[ni], mk, 64);
      uint o2 = (uint)__shfl_xor((int)t2[ni], mk, 64);
      uint o3 = (uint)__shfl_xor((int)t3[ni], mk, 64);
      INS(t1[ni], t2[ni], t3[ni], o1);
      INS(t1[ni], t2[ni], t3[ni], o2);
      INS(t1[ni], t2[ni], t3[ni], o3);
    }
  }

  uint* scK = (uint*)lds;        // [4 wr][128 xloc][3] = 6 KB
  if (grp == 0) {
    #pragma unroll
    for (int ni = 0; ni < 4; ++ni) {
      int xloc = wc * 64 + ni * 16 + l15;
      uint* p = &scK[(wr * 128 + xloc) * 3];
      p[0] = t1[ni]; p[1] = t2[ni]; p[2] = t3[ni];
    }
  }
  __syncthreads();
  if (tid < 256) {
    int xr = tid & 127;
    int s  = tid >> 7;
    const uint* pa = &scK[((2 * s) * 128 + xr) * 3];
    const uint* pb = &scK[((2 * s + 1) * 128 + xr) * 3];
    uint a1 = pa[0], a2 = pa[1], a3 = pa[2];
    #pragma unroll
    for (int z = 0; z < 3; ++z) INS(a1, a2, a3, pb[z]);
    float v1 = keyval(a1), v2 = keyval(a2), v3 = keyval(a3);
    uint i1 = a1 & 127u, i2 = a2 & 127u;
    uint d2 = min(255u, (uint)((v2 - v1) * 4.0f));   // floor -> conservative-low
    uint d3 = min(255u, (uint)((v3 - v1) * 4.0f));
    uint2 st;
    st.x = __float_as_uint(v1);
    st.y = i1 | (i2 << 7) | (d2 << 14) | (d3 << 22);
    stats[(size_t)(rowBase + xr) * NTILES + nTile * 2 + s] = st;
  }
#undef INS
}

// ---------------- fp64 refinement core ----------------

__device__ inline double dist64(const float4& xa, const float4& xb,
                                const float4& ca, const float4& cv, int lane) {
  double s = 0.0, d;
  d = (double)xa.x - (double)ca.x; s += d*d;
  d = (double)xa.y - (double)ca.y; s += d*d;
  d = (double)xa.z - (double)ca.z; s += d*d;
  d = (double)xa.w - (double)ca.w; s += d*d;
  d = (double)xb.x - (double)cv.x; s += d*d;
  d = (double)xb.y - (double)cv.y; s += d*d;
  d = (double)xb.z - (double)cv.z; s += d*d;
  d = (double)xb.w - (double)cv.w; s += d*d;
  #pragma unroll
  for (int m = 1; m < 64; m <<= 1) s += shfl_xor_dbl(s, m);
  return s;
}

__device__ inline void upd(double s, int col, double& best, int& bi) {
  if (s < best || (s == best && col < bi)) { best = s; bi = col; }
}

__device__ inline void eval64_pair(const float4& xa, const float4& xb,
                                   const float* __restrict__ cb, int colA, int colB,
                                   bool hasB, double& best, int& bi, int lane) {
  const float* crA = cb + (size_t)colA * DDIM + lane * 8;
  float4 a0 = *(const float4*)crA;
  float4 a1 = *(const float4*)(crA + 4);
  float4 b0, b1;
  if (hasB) {
    const float* crB = cb + (size_t)colB * DDIM + lane * 8;
    b0 = *(const float4*)crB;
    b1 = *(const float4*)(crB + 4);
  }
  double sA = dist64(xa, xb, a0, a1, lane);
  upd(sA, colA, best, bi);
  if (hasB) {
    double sB = dist64(xa, xb, b0, b1, lane);
    upd(sB, colB, best, bi);
  }
}

__device__ inline int refine_row(int n, int lane,
                                 const float* __restrict__ x, const float* __restrict__ cb,
                                 const float* __restrict__ cnorm,
                                 const uint2* __restrict__ stats) {
  uint2 st = stats[(size_t)n * NTILES + lane];
  float m1 = __uint_as_float(st.x);
  int   i1 = st.y & 127, i2 = (st.y >> 7) & 127;
  float m2 = m1 + ((st.y >> 14) & 255u) * 0.25f;
  float m3 = m1 + ((st.y >> 22) & 255u) * 0.25f;
  float g = m1;
  #pragma unroll
  for (int m = 1; m < 64; m <<= 1) g = fminf(g, __shfl_xor(g, m, 64));
  float T = g + MARGIN;
  unsigned long long q1 = __ballot(m1 <= T);
  unsigned long long q2 = __ballot(m2 <= T);
  unsigned long long qr = __ballot(m3 <= T);

  // fast path: singleton candidate set -> it IS the argmin (no loads needed)
  if (q2 == 0 && qr == 0 && (q1 & (q1 - 1)) == 0) {
    int t = __ffsll(q1) - 1;
    return t * 128 + __shfl(i1, t, 64);
  }

  const float* xr = x + (size_t)n * DDIM;
  float4 xa = *(const float4*)(xr + lane * 8);
  float4 xb = *(const float4*)(xr + lane * 8 + 4);

  double best = 1e300;
  int bi = 0x7fffffff;

  while (q1) {
    int t0 = __ffsll(q1) - 1; q1 &= q1 - 1;
    int colA = t0 * 128 + __shfl(i1, t0, 64);
    int colB = 0; bool hasB = false;
    if (q1) {
      int tB = __ffsll(q1) - 1; q1 &= q1 - 1;
      colB = tB * 128 + __shfl(i1, tB, 64);
      hasB = true;
    }
    eval64_pair(xa, xb, cb, colA, colB, hasB, best, bi, lane);
  }
  while (q2) {
    int t0 = __ffsll(q2) - 1; q2 &= q2 - 1;
    int colA = t0 * 128 + __shfl(i2, t0, 64);
    int colB = 0; bool hasB = false;
    if (q2) {
      int tB = __ffsll(q2) - 1; q2 &= q2 - 1;
      colB = tB * 128 + __shfl(i2, tB, 64);
      hasB = true;
    }
    eval64_pair(xa, xb, cb, colA, colB, hasB, best, bi, lane);
  }
  while (qr) {
    int t = __ffsll(qr) - 1; qr &= qr - 1;
    for (int c2 = 0; c2 < 128; ++c2) {
      int col2 = t * 128 + c2;
      const float* cr = cb + (size_t)col2 * DDIM + lane * 8;
      float4 ca = *(const float4*)cr;
      float4 cv = *(const float4*)(cr + 4);
      float p = xa.x*ca.x + xa.y*ca.y + xa.z*ca.z + xa.w*ca.w
              + xb.x*cv.x + xb.y*cv.y + xb.z*cv.z + xb.w*cv.w;
      #pragma unroll
      for (int m = 1; m < 64; m <<= 1) p += __shfl_xor(p, m, 64);
      float s32 = cnorm[col2] - 2.0f * p;
      if (s32 <= T) {
        double s = dist64(xa, xb, ca, cv, lane);
        upd(s, col2, best, bi);
      }
    }
  }
  return bi;
}

__global__ __launch_bounds__(256) void k_refine(
    const float* __restrict__ x, const float* __restrict__ cb,
    const float* __restrict__ cnorm, const uint2* __restrict__ stats,
    unsigned int* __restrict__ bestOut)
{
  int n = blockIdx.x * 4 + (threadIdx.x >> 6);
  int lane = threadIdx.x & 63;
  int bi = refine_row(n, lane, x, cb, cnorm, stats);
  if (lane == 0) bestOut[n] = (unsigned int)bi;
}

__global__ __launch_bounds__(256) void k_refine_gather(
    const float* __restrict__ x, const float* __restrict__ cb,
    const float* __restrict__ cnorm, const uint2* __restrict__ stats,
    float* __restrict__ out)
{
  int n = blockIdx.x * 4 + (threadIdx.x >> 6);
  int lane = threadIdx.x & 63;
  int bi = refine_row(n, lane, x, cb, cnorm, stats);
  const float4* s = (const float4*)(cb + (size_t)bi * DDIM);
  float4* dp = (float4*)(out + (size_t)n * DDIM);
  dp[lane * 2]     = s[lane * 2];
  dp[lane * 2 + 1] = s[lane * 2 + 1];
}

__global__ __launch_bounds__(256) void k_gather(const float* __restrict__ cb,
                                                const unsigned int* __restrict__ bestIdx,
                                                float* __restrict__ out) {
  int n = blockIdx.x * 4 + (threadIdx.x >> 6);
  int lane = threadIdx.x & 63;
  unsigned int b = bestIdx[n];
  const float4* s = (const float4*)(cb + (size_t)b * DDIM);
  float4* dp = (float4*)(out + (size_t)n * DDIM);
  dp[lane * 2]     = s[lane * 2];
  dp[lane * 2 + 1] = s[lane * 2 + 1];
}

// ---------------- launch ----------------

extern "C" void kernel_launch(void* const* d_in, const int* in_sizes, int n_in,
                              void* d_out, int out_size, void* d_ws, size_t ws_size,
                              hipStream_t stream) {
  const float* x  = (const float*)d_in[0];   // [16384, 512]
  const float* cb = (const float*)d_in[1];   // [8192, 512]
  float* out = (float*)d_out;

  char* ob = (char*)d_out;
  u16* Xbf = (u16*)ob;                          // [0,16M)
  u16* Cbf = (u16*)(ob + 16ull * 1024 * 1024);  // [16M,24M)

  char* wsb = (char*)d_ws;
  float* cnorm = (float*)wsb;                               // 32 KB
  unsigned int* bestIdx = (unsigned int*)(wsb + 32 * 1024); // 64 KB

  const size_t statsBytes = (size_t)MROWS * NTILES * sizeof(uint2);  // 8 MB
  bool fuse = ws_size >= 96 * 1024 + statsBytes;
  uint2* stats = fuse ? (uint2*)(wsb + 96 * 1024)
                      : (uint2*)(ob + 24ull * 1024 * 1024);

  (void)hipFuncSetAttribute((const void*)k_gemm_min,
                            hipFuncAttributeMaxDynamicSharedMemorySize, 49152);

  k_conv    <<<6144, 256, 0, stream>>>(x, cb, Xbf, Cbf, cnorm);
  k_gemm_min<<<4096, 512, 49152, stream>>>(Xbf, Cbf, cnorm, stats);
  if (fuse) {
    k_refine_gather<<<4096, 256, 0, stream>>>(x, cb, cnorm, stats, out);
  } else {
    k_refine<<<4096, 256, 0, stream>>>(x, cb, cnorm, stats, bestIdx);
    k_gather<<<4096, 256, 0, stream>>>(cb, bestIdx, out);
  }
}